// Round 4
// baseline (1927.046 us; speedup 1.0000x reference)
//
#include <hip/hip_runtime.h>

#define BB 2048
#define K 32
#define ROW 2056          // L1 + P floats per fp32 ft_weight row
#define L1D 2048
#define NFEAT 22528
#define NE 131072         // 2 * B * K entries

typedef unsigned short us8 __attribute__((ext_vector_type(8)));
typedef signed char    c8  __attribute__((ext_vector_type(8)));
typedef float          f8  __attribute__((ext_vector_type(8)));

// int8 table scale: clamp +-0.0625, step exactly representable
#define S_T   (0.0625f / 128.0f)     // 4.8828125e-4
#define INV_S (128.0f / 0.0625f)     // 2048.0

// workspace layout:
//   tblT  : int8 transposed table [256 col-tiles][NFEAT][8]   46,137,344
//   w1bf  : bf16 W1 [8][16][2048]                                 524,288
//   psqtc : fp32 psqt compact [NFEAT][8]                          720,896
//   csr   : uint2 [NE]  (meta = f<<12 | side<<11 | sample)      1,048,576
//   accW  : fp32 [2048][2048]                                  16,777,216
//   accB  : fp32 [2048][2048]                                  16,777,216
#define TBLT_BYTES ((size_t)NFEAT * 2048)
#define W1_ELEMS   ((size_t)8 * 16 * L1D)
#define W1_OFF     TBLT_BYTES                         // 46,137,344
#define PSQ_OFF    (W1_OFF + W1_ELEMS * 2)            // 46,661,632
#define CSR_OFF    (PSQ_OFF + (size_t)NFEAT * 8 * 4)  // 47,382,528
#define ACCW_OFF   (CSR_OFF + (size_t)NE * 8)         // 48,431,104
#define ACCB_OFF   (ACCW_OFF + (size_t)BB * L1D * 4)  // 65,208,320
#define WS_NEEDED  (ACCB_OFF + (size_t)BB * L1D * 4)  // 81,985,536

// conv chunk counts
#define TBL_N32 ((NFEAT / 4) * 256)                   // 4-row int8 groups: 1,441,792
#define W1_N8   ((int)(W1_ELEMS / 8))                 // 32,768
#define CONV_N  (TBL_N32 + W1_N8 + NFEAT)

__device__ __forceinline__ float bf2f(unsigned short s) {
    union { unsigned int u; float f; } v; v.u = ((unsigned int)s) << 16; return v.f;
}

__device__ __forceinline__ unsigned short f2bf(float f) {
    union { float f; unsigned int u; } v; v.f = f;
    const unsigned int u = v.u;
    return (unsigned short)((u + 0x7fffu + ((u >> 16) & 1u)) >> 16);  // RNE; finite
}

__device__ __forceinline__ signed char f2i8(float f) {
    return (signed char)(int)rintf(fminf(fmaxf(f * INV_S, -127.f), 127.f));
}

__device__ __forceinline__ void fma4(float4& a, float v, const float4 t) {
    a.x = fmaf(v, t.x, a.x); a.y = fmaf(v, t.y, a.y);
    a.z = fmaf(v, t.z, a.z); a.w = fmaf(v, t.w, a.w);
}

__device__ __forceinline__ float4 add4(float4 a, float4 b) {
    float4 r; r.x = a.x + b.x; r.y = a.y + b.y; r.z = a.z + b.z; r.w = a.w + b.w;
    return r;
}

__device__ __forceinline__ float4 mix4(float ua, float4 a, float ub, float4 b) {
    float4 r;
    r.x = fmaf(ua, a.x, ub * b.x); r.y = fmaf(ua, a.y, ub * b.y);
    r.z = fmaf(ua, a.z, ub * b.z); r.w = fmaf(ua, a.w, ub * b.w);
    return r;
}

__device__ __forceinline__ float lsq1(float g, float s) {
    return rintf(fminf(fmaxf(g / s, 0.f), 255.f)) * s;
}

__device__ __forceinline__ float4 lsq4(float4 g, float s) {
    float4 r;
    r.x = lsq1(g.x, s); r.y = lsq1(g.y, s); r.z = lsq1(g.z, s); r.w = lsq1(g.w, s);
    return r;
}

__device__ __forceinline__ float4 mul4(float4 a, float4 b) {
    float4 r; r.x = a.x * b.x; r.y = a.y * b.y; r.z = a.z * b.z; r.w = a.w * b.w;
    return r;
}

// ---- conv: fp32 -> transposed int8 table + bf16 W1 + compact fp32 psqt ----
// table part: thread quantizes 4 consecutive rows of one 8-col tile ->
// 32 B contiguous output (full write sectors); reads stay coalesced.
__global__ __launch_bounds__(256) void conv_all(const float* __restrict__ ftw,
                                                const float* __restrict__ W1,
                                                signed char* __restrict__ tblT,
                                                unsigned short* __restrict__ w1bf,
                                                float* __restrict__ psqtc) {
    int i = blockIdx.x * blockDim.x + threadIdx.x;
    const int stride = gridDim.x * blockDim.x;
    for (; i < CONV_N; i += stride) {
        if (i < TBL_N32) {
            const int c = i & 255;          // col tile (cols 8c..8c+8)
            const int rq = i >> 8;          // row quad, < NFEAT/4
            const int r0 = rq * 4;
            signed char* dst = tblT + ((size_t)c * NFEAT + r0) * 8;
            #pragma unroll
            for (int rr = 0; rr < 4; ++rr) {
                const float* src = ftw + (size_t)(r0 + rr) * ROW + c * 8;
                const float4 a = ((const float4*)src)[0];
                const float4 b = ((const float4*)src)[1];
                c8 o;
                o[0] = f2i8(a.x); o[1] = f2i8(a.y); o[2] = f2i8(a.z); o[3] = f2i8(a.w);
                o[4] = f2i8(b.x); o[5] = f2i8(b.y); o[6] = f2i8(b.z); o[7] = f2i8(b.w);
                *(c8*)(dst + rr * 8) = o;
            }
        } else if (i < TBL_N32 + W1_N8) {
            const int j = i - TBL_N32;
            const float* src = W1 + (size_t)j * 8;
            const float4 a = ((const float4*)src)[0];
            const float4 b = ((const float4*)src)[1];
            us8 o;
            o[0] = f2bf(a.x); o[1] = f2bf(a.y); o[2] = f2bf(a.z); o[3] = f2bf(a.w);
            o[4] = f2bf(b.x); o[5] = f2bf(b.y); o[6] = f2bf(b.z); o[7] = f2bf(b.w);
            *(us8*)(w1bf + (size_t)j * 8) = o;
        } else {
            const int r = i - TBL_N32 - W1_N8;
            const float4* src = (const float4*)(ftw + (size_t)r * ROW + 2048);
            float4* dst = (float4*)(psqtc + (size_t)r * 8);
            dst[0] = src[0]; dst[1] = src[1];   // exact fp32 copy of 8 psqt cols
        }
    }
}

// ---- CSR build: single block, 2 half-passes so the histogram fits in 48KB LDS ----
// meta = f<<12 | side<<11 | sample  (f < 2^15, sample < 2^11)
__global__ __launch_bounds__(1024) void csr_build(const int* __restrict__ widx,
                                                  const float* __restrict__ wval,
                                                  const int* __restrict__ bidx,
                                                  const float* __restrict__ bval,
                                                  uint2* __restrict__ csr) {
    __shared__ unsigned int hist[11264];   // 45,056 B  (NFEAT/2 bins per pass)
    __shared__ unsigned int tsum[1024];
    const int t = threadIdx.x;
    unsigned int base = 0;
    for (int half = 0; half < 2; ++half) {
        const unsigned int lo = half * 11264u, hi = lo + 11264u;
        for (int i = t; i < 11264; i += 1024) hist[i] = 0u;
        __syncthreads();
        // count
        for (int e = t; e < NE / 2; e += 1024) {
            unsigned int f = (unsigned int)widx[e];
            if (f >= lo && f < hi) atomicAdd(&hist[f - lo], 1u);
            f = (unsigned int)bidx[e];
            if (f >= lo && f < hi) atomicAdd(&hist[f - lo], 1u);
        }
        __syncthreads();
        // per-thread partials over 11 bins
        unsigned int cnt[11];
        unsigned int run = 0;
        const int bbase = t * 11;
        #pragma unroll
        for (int j = 0; j < 11; ++j) { cnt[j] = hist[bbase + j]; run += cnt[j]; }
        tsum[t] = run;
        __syncthreads();
        // Hillis-Steele inclusive scan over 1024 thread totals
        for (int d = 1; d < 1024; d <<= 1) {
            const unsigned int v = (t >= d) ? tsum[t - d] : 0u;
            __syncthreads();
            tsum[t] += v;
            __syncthreads();
        }
        const unsigned int halftot = tsum[1023];
        unsigned int ex = base + ((t == 0) ? 0u : tsum[t - 1]);
        #pragma unroll
        for (int j = 0; j < 11; ++j) { hist[bbase + j] = ex; ex += cnt[j]; }
        __syncthreads();
        // scatter this half's entries
        for (int e = t; e < NE / 2; e += 1024) {
            const unsigned int s = (unsigned int)(e >> 5);   // K = 32
            unsigned int f = (unsigned int)widx[e];
            if (f >= lo && f < hi) {
                const unsigned int p = atomicAdd(&hist[f - lo], 1u);
                csr[p] = make_uint2((f << 12) | s, __float_as_uint(wval[e]));
            }
            f = (unsigned int)bidx[e];
            if (f >= lo && f < hi) {
                const unsigned int p = atomicAdd(&hist[f - lo], 1u);
                csr[p] = make_uint2((f << 12) | (1u << 11) | s, __float_as_uint(bval[e]));
            }
        }
        __syncthreads();
        base += halftot;
    }
}

// ---- phase1: streaming scatter-accumulate ----
// 512 blocks: blockIdx>>8 = side, blockIdx&255 = 8-col tile. LDS holds this
// tile's accumulator for ALL 2048 samples (stride 9 -> full 32-bank spread for
// random-sample ds_add_f32). Entries arrive feature-sorted, so the table-slice
// reads are a forward stream (L1-hot window).
__global__ __launch_bounds__(256, 2) void phase1(const signed char* __restrict__ tblT,
                                                 const uint2* __restrict__ csr,
                                                 float* __restrict__ accW,
                                                 float* __restrict__ accB) {
    __shared__ float acc[2048 * 9];   // 73,728 B -> 2 blocks/CU
    const int side = blockIdx.x >> 8;
    const int c    = blockIdx.x & 255;
    const int t    = threadIdx.x;
    for (int i = t; i < 2048 * 9; i += 256) acc[i] = 0.f;
    __syncthreads();
    const signed char* slice = tblT + (size_t)c * NFEAT * 8;
    const unsigned int want = (unsigned int)side << 11;
    #pragma unroll 4
    for (int e = t; e < NE; e += 256) {
        const uint2 E = csr[e];
        const unsigned int meta = E.x;
        if ((meta & (1u << 11)) != want) continue;
        const unsigned int f = meta >> 12;
        const unsigned int s = meta & 2047u;
        const float v = __uint_as_float(E.y);
        const c8 r = *(const c8*)(slice + (size_t)f * 8);
        float* a = acc + s * 9;
        #pragma unroll
        for (int j = 0; j < 8; ++j) atomicAdd(a + j, v * (float)r[j]);
    }
    __syncthreads();
    float* dst = side ? accB : accW;
    for (int s = t; s < 2048; s += 256) {
        f8 o;
        #pragma unroll
        for (int j = 0; j < 8; ++j) o[j] = acc[s * 9 + j];
        *(f8*)(dst + (size_t)s * L1D + c * 8) = o;
    }
}

// ---- phase2 shared-memory block ----
struct __align__(32) SBuf {
    float aw[2048];   // qa -> m[0:1024) pair-products in chunks [0:128)
    float ab[2048];   // qb -> m[1024:2048)
    float h1t[16];
    float h1[16];
    float h2[32];
    float psq;
};

// ---- phase2: per-sample tail (mix/LSQ/pairwise/W1/W2/Wo + psqt) ----
__global__ __launch_bounds__(256, 4) void phase2(
    const float* __restrict__ us_p, const float* __restrict__ them_p,
    const int* __restrict__ widx, const float* __restrict__ wval,
    const int* __restrict__ bidx, const float* __restrict__ bval,
    const int* __restrict__ psqt_idx, const int* __restrict__ ls_idx,
    const float* __restrict__ ftb, const float* __restrict__ lsq_s,
    const float* __restrict__ accW, const float* __restrict__ accB,
    const unsigned short* __restrict__ w1bf, const float* __restrict__ psqtc,
    const float* __restrict__ b1, const float* __restrict__ W2,
    const float* __restrict__ b2, const float* __restrict__ Wo,
    const float* __restrict__ bo, float* __restrict__ out)
{
    __shared__ SBuf sb;
    const int b = blockIdx.x;
    const int t = threadIdx.x;
    const int kb = b * K;

    const float usv = us_p[b];
    const float thv = them_p[b];

    // ---- read raw accumulators (coalesced 32-B) + bias + mix + LSQ ----
    const f8 awr = *(const f8*)(accW + (size_t)b * L1D + t * 8);
    const f8 abr = *(const f8*)(accB + (size_t)b * L1D + t * 8);
    const f8 fb8 = ((const f8*)ftb)[t];
    const float s0 = lsq_s[0], s1 = lsq_s[1], s2 = lsq_s[2], s3 = lsq_s[3];
    const float sA = (t < 128) ? s0 : s1;   // cols [0,1024) vs [1024,2048)
    const float sB = (t < 128) ? s2 : s3;
    f8 qa, qb;
    #pragma unroll
    for (int j = 0; j < 8; ++j) {
        const float aw = fmaf(awr[j], S_T, fb8[j]);
        const float ab = fmaf(abr[j], S_T, fb8[j]);
        qa[j] = lsq1(fmaf(usv, aw, thv * ab), sA);
        qb[j] = lsq1(fmaf(usv, ab, thv * aw), sB);
    }
    ((f8*)sb.aw)[t] = qa;
    ((f8*)sb.ab)[t] = qb;

    // ---- psqt from compact L2-resident table (ft_bias cancels in wps-bps) ----
    const int pi = psqt_idx[b];
    if (t < 64) {
        const int k = t & 31;
        const int   idx = (t < 32) ? widx[kb + k] : bidx[kb + k];
        const float val = (t < 32) ? wval[kb + k] : bval[kb + k];
        float c = val * psqtc[(size_t)idx * 8 + pi];
        c += __shfl_down(c, 16, 32); c += __shfl_down(c, 8, 32);
        c += __shfl_down(c, 4, 32);  c += __shfl_down(c, 2, 32);
        c += __shfl_down(c, 1, 32);
        const float bsum = __shfl(c, 32);
        if (t == 0) sb.psq = (c - bsum) * (usv - 0.5f);
    }
    __syncthreads();

    // ---- pairwise product ----
    if (t < 128) {
        const f8 x = ((const f8*)sb.aw)[t];
        const f8 y = ((const f8*)sb.aw)[t + 128];
        ((f8*)sb.aw)[t] = x * y;
    } else {
        const f8 x = ((const f8*)sb.ab)[t - 128];
        const f8 y = ((const f8*)sb.ab)[t];
        ((f8*)sb.ab)[t - 128] = x * y;
    }
    __syncthreads();

    // ---- h1 = clip(W1[i] @ m + b1[i]); 16 threads/output ----
    const int i = ls_idx[b];
    {
        const int o   = t >> 4;
        const int sub = t & 15;
        const us8* Wrow = (const us8*)(w1bf + (((size_t)i * 16 + o) << 11));
        f8 a8 = (f8)0.f;
        #pragma unroll
        for (int jj = 0; jj < 8; ++jj) {
            const int c = sub + (jj << 4);
            const f8 m = ((const f8*)sb.aw)[c];
            const us8 w = Wrow[c];
            #pragma unroll
            for (int j = 0; j < 8; ++j) a8[j] = fmaf(m[j], bf2f(w[j]), a8[j]);
        }
        #pragma unroll
        for (int jj = 8; jj < 16; ++jj) {
            const int c = sub + ((jj - 8) << 4);
            const f8 m = ((const f8*)sb.ab)[c];
            const us8 w = Wrow[sub + (jj << 4)];
            #pragma unroll
            for (int j = 0; j < 8; ++j) a8[j] = fmaf(m[j], bf2f(w[j]), a8[j]);
        }
        float acc1 = ((a8[0]+a8[1]) + (a8[2]+a8[3])) + ((a8[4]+a8[5]) + (a8[6]+a8[7]));
        acc1 += __shfl_down(acc1, 8, 16); acc1 += __shfl_down(acc1, 4, 16);
        acc1 += __shfl_down(acc1, 2, 16); acc1 += __shfl_down(acc1, 1, 16);
        if (sub == 0) sb.h1t[o] = acc1;
    }
    __syncthreads();

    if (t < 16) {
        const float v = sb.h1t[t] + b1[i * 16 + t];
        sb.h1[t] = fminf(fmaxf(v, 0.f), 1.f);
    }
    __syncthreads();

    if (t < 32) {
        const float* W2i = W2 + (size_t)i * 32 * 16 + t * 16;
        float v = b2[i * 32 + t];
        #pragma unroll
        for (int j = 0; j < 16; ++j) v = fmaf(sb.h1[j], W2i[j], v);
        sb.h2[t] = fminf(fmaxf(v, 0.f), 1.f);
    }
    __syncthreads();

    if (t == 0) {
        const float* Woi = Wo + (size_t)i * 32;
        float v = bo[i];
        #pragma unroll
        for (int j = 0; j < 32; ++j) v = fmaf(sb.h2[j], Woi[j], v);
        out[b] = v + sb.psq;
    }
}

// ---- fallback: fully fused fp32 (only if ws too small) ----
__global__ __launch_bounds__(512, 4) void nnue_fwd_f32(
    const float* __restrict__ us_p, const float* __restrict__ them_p,
    const int* __restrict__ widx, const float* __restrict__ wval,
    const int* __restrict__ bidx, const float* __restrict__ bval,
    const int* __restrict__ psqt_idx, const int* __restrict__ ls_idx,
    const float* __restrict__ ftw, const float* __restrict__ ftb,
    const float* __restrict__ lsq_s, const float* __restrict__ W1,
    const float* __restrict__ b1, const float* __restrict__ W2,
    const float* __restrict__ b2, const float* __restrict__ Wo,
    const float* __restrict__ bo, float* __restrict__ out)
{
    const int b = blockIdx.x;
    const int t = threadIdx.x;
    __shared__ float4 sQA[512]; __shared__ float4 sQB[512]; __shared__ float4 sMx[512];
    __shared__ float sH1t[16]; __shared__ float sH1[16]; __shared__ float sH2[32];
    __shared__ float sPsq;
    const float usv = us_p[b]; const float thv = them_p[b];
    float4 aw = {0,0,0,0}, ab = {0,0,0,0};
    #pragma unroll 4
    for (int k = 0; k < K; ++k) {
        const int iw = widx[b*K+k]; const float vw = wval[b*K+k];
        const int ibx = bidx[b*K+k]; const float vb = bval[b*K+k];
        fma4(aw, vw, ((const float4*)(ftw + (size_t)iw * ROW))[t]);
        fma4(ab, vb, ((const float4*)(ftw + (size_t)ibx * ROW))[t]);
    }
    const int pi = psqt_idx[b];
    if (t < 64) {
        const int k = t & 31;
        const int   idx = (t < 32) ? widx[b*K+k] : bidx[b*K+k];
        const float val = (t < 32) ? wval[b*K+k] : bval[b*K+k];
        float cc = val * ftw[(size_t)idx * ROW + 2048 + pi];
        cc += __shfl_down(cc, 16, 32); cc += __shfl_down(cc, 8, 32);
        cc += __shfl_down(cc, 4, 32); cc += __shfl_down(cc, 2, 32); cc += __shfl_down(cc, 1, 32);
        const float bsum = __shfl(cc, 32);
        if (t == 0) sPsq = (cc - bsum) * (usv - 0.5f);
    }
    const float s0 = lsq_s[0], s1 = lsq_s[1], s2 = lsq_s[2], s3 = lsq_s[3];
    const float4 bias = ((const float4*)ftb)[t];
    aw = add4(aw, bias); ab = add4(ab, bias);
    const float sA = (t < 256) ? s0 : s1;
    const float sB = (t < 256) ? s2 : s3;
    sQA[t] = lsq4(mix4(usv, aw, thv, ab), sA);
    sQB[t] = lsq4(mix4(usv, ab, thv, aw), sB);
    __syncthreads();
    if (t < 256) { sMx[t] = mul4(sQA[t], sQA[t+256]); sMx[t+256] = mul4(sQB[t], sQB[t+256]); }
    __syncthreads();
    const int i = ls_idx[b];
    const float* W1i = W1 + (size_t)i * 16 * L1D;
    {
        const int o = t >> 5; const int sub = t & 31;
        const float4* Wrow = (const float4*)(W1i + o * L1D);
        float4 a4 = {0,0,0,0};
        #pragma unroll
        for (int jj = 0; jj < 16; ++jj) {
            const int j4 = sub + (jj << 5);
            const float4 m = sMx[j4]; const float4 w = Wrow[j4];
            a4.x = fmaf(m.x, w.x, a4.x); a4.y = fmaf(m.y, w.y, a4.y);
            a4.z = fmaf(m.z, w.z, a4.z); a4.w = fmaf(m.w, w.w, a4.w);
        }
        float acc = (a4.x + a4.y) + (a4.z + a4.w);
        acc += __shfl_down(acc, 16, 32); acc += __shfl_down(acc, 8, 32);
        acc += __shfl_down(acc, 4, 32); acc += __shfl_down(acc, 2, 32); acc += __shfl_down(acc, 1, 32);
        if (sub == 0) sH1t[o] = acc;
    }
    __syncthreads();
    if (t < 16) sH1[t] = fminf(fmaxf(sH1t[t] + b1[i*16+t], 0.f), 1.f);
    __syncthreads();
    if (t < 32) {
        const float* W2i = W2 + (size_t)i * 32 * 16 + t * 16;
        float v = b2[i*32+t];
        #pragma unroll
        for (int j = 0; j < 16; ++j) v = fmaf(sH1[j], W2i[j], v);
        sH2[t] = fminf(fmaxf(v, 0.f), 1.f);
    }
    __syncthreads();
    if (t == 0) {
        const float* Woi = Wo + (size_t)i * 32;
        float v = bo[i];
        #pragma unroll
        for (int j = 0; j < 32; ++j) v = fmaf(sH2[j], Woi[j], v);
        out[b] = v + sPsq;
    }
}

extern "C" void kernel_launch(void* const* d_in, const int* in_sizes, int n_in,
                              void* d_out, int out_size, void* d_ws, size_t ws_size,
                              hipStream_t stream) {
    const float* us_p  = (const float*)d_in[0];
    const float* them  = (const float*)d_in[1];
    const int*   widx  = (const int*)d_in[2];
    const float* wval  = (const float*)d_in[3];
    const int*   bidx  = (const int*)d_in[4];
    const float* bval  = (const float*)d_in[5];
    const int*   pidx  = (const int*)d_in[6];
    const int*   lidx  = (const int*)d_in[7];
    const float* ftw   = (const float*)d_in[8];
    const float* ftb   = (const float*)d_in[9];
    const float* lsqs  = (const float*)d_in[10];
    const float* W1    = (const float*)d_in[11];
    const float* b1    = (const float*)d_in[12];
    const float* W2    = (const float*)d_in[13];
    const float* b2    = (const float*)d_in[14];
    const float* Wo    = (const float*)d_in[15];
    const float* bo    = (const float*)d_in[16];
    float* out = (float*)d_out;

    if (ws_size >= WS_NEEDED) {
        signed char*    tblT  = (signed char*)d_ws;
        unsigned short* w1bf  = (unsigned short*)((char*)d_ws + W1_OFF);
        float*          psqtc = (float*)((char*)d_ws + PSQ_OFF);
        uint2*          csr   = (uint2*)((char*)d_ws + CSR_OFF);
        float*          accW  = (float*)((char*)d_ws + ACCW_OFF);
        float*          accB  = (float*)((char*)d_ws + ACCB_OFF);
        conv_all<<<dim3(8192), dim3(256), 0, stream>>>(ftw, W1, tblT, w1bf, psqtc);
        csr_build<<<dim3(1), dim3(1024), 0, stream>>>(widx, wval, bidx, bval, csr);
        phase1<<<dim3(512), dim3(256), 0, stream>>>(tblT, csr, accW, accB);
        phase2<<<dim3(BB), dim3(256), 0, stream>>>(
            us_p, them, widx, wval, bidx, bval, pidx, lidx,
            ftb, lsqs, accW, accB, w1bf, psqtc, b1, W2, b2, Wo, bo, out);
    } else {
        nnue_fwd_f32<<<dim3(BB), dim3(512), 0, stream>>>(
            us_p, them, widx, wval, bidx, bval, pidx, lidx,
            ftw, ftb, lsqs, W1, b1, W2, b2, Wo, bo, out);
    }
}

// Round 5
// 343.025 us; speedup vs baseline: 5.6178x; 5.6178x over previous
//
#include <hip/hip_runtime.h>

#define BB 2048
#define K 32
#define ROW 2056          // L1 + P floats per fp32 ft_weight row
#define L1D 2048
#define NFEAT 22528
#define NTILE 16
#define TCOLS 128         // int8 cols per tile (128 B row slice)

typedef unsigned short us8 __attribute__((ext_vector_type(8)));
typedef signed char    c8  __attribute__((ext_vector_type(8)));
typedef signed char    c16 __attribute__((ext_vector_type(16)));
typedef float          f8  __attribute__((ext_vector_type(8)));

// int8 table scale: clamp +-0.0625, step exactly representable
#define S_T   (0.0625f / 128.0f)     // 4.8828125e-4
#define INV_S (128.0f / 0.0625f)     // 2048.0

// workspace layout:
//   tblT  : int8 tiled table [NTILE][NFEAT][TCOLS]             46,137,344
//   w1bf  : bf16 W1 [8][16][2048]                                  524,288
//   psqtc : fp32 psqt compact [NFEAT][8]                           720,896
//   accW  : fp32 [2048][2048]                                   16,777,216
//   accB  : fp32 [2048][2048]                                   16,777,216
#define TBLT_BYTES ((size_t)NFEAT * 2048)
#define W1_ELEMS   ((size_t)8 * 16 * L1D)
#define W1_OFF     TBLT_BYTES                         // 46,137,344
#define PSQ_OFF    (W1_OFF + W1_ELEMS * 2)            // 46,661,632
#define ACCW_OFF   (PSQ_OFF + (size_t)NFEAT * 8 * 4)  // 47,382,528
#define ACCB_OFF   (ACCW_OFF + (size_t)BB * L1D * 4)  // 64,159,744
#define WS_NEEDED  (ACCB_OFF + (size_t)BB * L1D * 4)  // 80,936,960

// conv chunk counts
#define TBL_N8  (NFEAT * 256)                         // 8-col groups
#define W1_N8   ((int)(W1_ELEMS / 8))                 // 32,768
#define CONV_N  (TBL_N8 + W1_N8 + NFEAT)

__device__ __forceinline__ float bf2f(unsigned short s) {
    union { unsigned int u; float f; } v; v.u = ((unsigned int)s) << 16; return v.f;
}

__device__ __forceinline__ unsigned short f2bf(float f) {
    union { float f; unsigned int u; } v; v.f = f;
    const unsigned int u = v.u;
    return (unsigned short)((u + 0x7fffu + ((u >> 16) & 1u)) >> 16);  // RNE; finite
}

__device__ __forceinline__ signed char f2i8(float f) {
    return (signed char)(int)rintf(fminf(fmaxf(f * INV_S, -127.f), 127.f));
}

__device__ __forceinline__ void fma4(float4& a, float v, const float4 t) {
    a.x = fmaf(v, t.x, a.x); a.y = fmaf(v, t.y, a.y);
    a.z = fmaf(v, t.z, a.z); a.w = fmaf(v, t.w, a.w);
}

__device__ __forceinline__ float4 add4(float4 a, float4 b) {
    float4 r; r.x = a.x + b.x; r.y = a.y + b.y; r.z = a.z + b.z; r.w = a.w + b.w;
    return r;
}

__device__ __forceinline__ float4 mix4(float ua, float4 a, float ub, float4 b) {
    float4 r;
    r.x = fmaf(ua, a.x, ub * b.x); r.y = fmaf(ua, a.y, ub * b.y);
    r.z = fmaf(ua, a.z, ub * b.z); r.w = fmaf(ua, a.w, ub * b.w);
    return r;
}

__device__ __forceinline__ float lsq1(float g, float s) {
    return rintf(fminf(fmaxf(g / s, 0.f), 255.f)) * s;
}

__device__ __forceinline__ float4 lsq4(float4 g, float s) {
    float4 r;
    r.x = lsq1(g.x, s); r.y = lsq1(g.y, s); r.z = lsq1(g.z, s); r.w = lsq1(g.w, s);
    return r;
}

__device__ __forceinline__ float4 mul4(float4 a, float4 b) {
    float4 r; r.x = a.x * b.x; r.y = a.y * b.y; r.z = a.z * b.z; r.w = a.w * b.w;
    return r;
}

// ---- conv: fp32 -> tiled int8 table + bf16 W1 + compact fp32 psqt ----
// tblT[tile][row][col]: tile = c>>4, col = (c&15)*8 for 8-col group c.
__global__ __launch_bounds__(256) void conv_all(const float* __restrict__ ftw,
                                                const float* __restrict__ W1,
                                                signed char* __restrict__ tblT,
                                                unsigned short* __restrict__ w1bf,
                                                float* __restrict__ psqtc) {
    int i = blockIdx.x * blockDim.x + threadIdx.x;
    const int stride = gridDim.x * blockDim.x;
    for (; i < CONV_N; i += stride) {
        if (i < TBL_N8) {
            const int row = i >> 8, c = i & 255;
            const float* src = ftw + (size_t)row * ROW + c * 8;
            const float4 a = ((const float4*)src)[0];
            const float4 b = ((const float4*)src)[1];
            c8 o;
            o[0] = f2i8(a.x); o[1] = f2i8(a.y); o[2] = f2i8(a.z); o[3] = f2i8(a.w);
            o[4] = f2i8(b.x); o[5] = f2i8(b.y); o[6] = f2i8(b.z); o[7] = f2i8(b.w);
            signed char* dst = tblT + ((size_t)(c >> 4) * NFEAT + row) * TCOLS + (c & 15) * 8;
            *(c8*)dst = o;
        } else if (i < TBL_N8 + W1_N8) {
            const int j = i - TBL_N8;
            const float* src = W1 + (size_t)j * 8;
            const float4 a = ((const float4*)src)[0];
            const float4 b = ((const float4*)src)[1];
            us8 o;
            o[0] = f2bf(a.x); o[1] = f2bf(a.y); o[2] = f2bf(a.z); o[3] = f2bf(a.w);
            o[4] = f2bf(b.x); o[5] = f2bf(b.y); o[6] = f2bf(b.z); o[7] = f2bf(b.w);
            *(us8*)(w1bf + (size_t)j * 8) = o;
        } else {
            const int r = i - TBL_N8 - W1_N8;
            const float4* src = (const float4*)(ftw + (size_t)r * ROW + 2048);
            float4* dst = (float4*)(psqtc + (size_t)r * 8);
            dst[0] = src[0]; dst[1] = src[1];   // exact fp32 copy of 8 psqt cols
        }
    }
}

// ---- gather, column-tiled + XCD-pinned ----
// 2048 blocks; bid -> xcd = bid&7, tile = xcd*2 + ((bid>>3)&1), chunk = bid>>4.
// Tile slice (NFEAT x 128 B = 2.75 MB) stays resident in that XCD's L2.
// Block: 16 samples x 2 sides; 8-lane group per (sample,side); lane owns 16 cols.
// Register accumulation, single coalesced write -> no atomics anywhere.
__global__ __launch_bounds__(256, 4) void gather_tiled(
    const signed char* __restrict__ tblT,
    const int* __restrict__ widx, const float* __restrict__ wval,
    const int* __restrict__ bidx, const float* __restrict__ bval,
    float* __restrict__ accW, float* __restrict__ accB)
{
    const int bid  = blockIdx.x;
    const int tile = ((bid & 7) << 1) | ((bid >> 3) & 1);
    const int chunk = bid >> 4;                 // 0..127
    const int t = threadIdx.x;
    const int g = t >> 3;                        // 0..31
    const int lane = t & 7;                      // 16-B sub-slice
    const int side = g >> 4;                     // 0: white, 1: black
    const int s = chunk * 16 + (g & 15);         // sample

    const int*   idxp = side ? bidx : widx;
    const float* valp = side ? bval : wval;
    const int kb = s * K;
    const signed char* slice = tblT + (size_t)tile * NFEAT * TCOLS + lane * 16;

    float acc[16];
    #pragma unroll
    for (int j = 0; j < 16; ++j) acc[j] = 0.f;

    #pragma unroll 4
    for (int k = 0; k < K; ++k) {
        const int   f = idxp[kb + k];            // L1-hot (128-B line covers all k)
        const float v = valp[kb + k];
        const c16 l = *(const c16*)(slice + (size_t)f * TCOLS);
        #pragma unroll
        for (int j = 0; j < 16; ++j) acc[j] = fmaf(v, (float)l[j], acc[j]);
    }

    float* dst = (side ? accB : accW) + (size_t)s * L1D + tile * TCOLS + lane * 16;
    f8 lo, hi;
    #pragma unroll
    for (int j = 0; j < 8; ++j) { lo[j] = acc[j]; hi[j] = acc[j + 8]; }
    ((f8*)dst)[0] = lo;
    ((f8*)dst)[1] = hi;
}

// ---- phase2 shared-memory block ----
struct __align__(32) SBuf {
    float aw[2048];   // qa -> m[0:1024) pair-products in chunks [0:128)
    float ab[2048];   // qb -> m[1024:2048)
    float h1t[16];
    float h1[16];
    float h2[32];
    float psq;
};

// ---- phase2: per-sample tail (mix/LSQ/pairwise/W1/W2/Wo + psqt) ----
__global__ __launch_bounds__(256, 4) void phase2(
    const float* __restrict__ us_p, const float* __restrict__ them_p,
    const int* __restrict__ widx, const float* __restrict__ wval,
    const int* __restrict__ bidx, const float* __restrict__ bval,
    const int* __restrict__ psqt_idx, const int* __restrict__ ls_idx,
    const float* __restrict__ ftb, const float* __restrict__ lsq_s,
    const float* __restrict__ accW, const float* __restrict__ accB,
    const unsigned short* __restrict__ w1bf, const float* __restrict__ psqtc,
    const float* __restrict__ b1, const float* __restrict__ W2,
    const float* __restrict__ b2, const float* __restrict__ Wo,
    const float* __restrict__ bo, float* __restrict__ out)
{
    __shared__ SBuf sb;
    const int b = blockIdx.x;
    const int t = threadIdx.x;
    const int kb = b * K;

    const float usv = us_p[b];
    const float thv = them_p[b];

    // ---- read raw accumulators (coalesced 32-B) + bias + mix + LSQ ----
    const f8 awr = *(const f8*)(accW + (size_t)b * L1D + t * 8);
    const f8 abr = *(const f8*)(accB + (size_t)b * L1D + t * 8);
    const f8 fb8 = ((const f8*)ftb)[t];
    const float s0 = lsq_s[0], s1 = lsq_s[1], s2 = lsq_s[2], s3 = lsq_s[3];
    const float sA = (t < 128) ? s0 : s1;   // cols [0,1024) vs [1024,2048)
    const float sB = (t < 128) ? s2 : s3;
    f8 qa, qb;
    #pragma unroll
    for (int j = 0; j < 8; ++j) {
        const float aw = fmaf(awr[j], S_T, fb8[j]);
        const float ab = fmaf(abr[j], S_T, fb8[j]);
        qa[j] = lsq1(fmaf(usv, aw, thv * ab), sA);
        qb[j] = lsq1(fmaf(usv, ab, thv * aw), sB);
    }
    ((f8*)sb.aw)[t] = qa;
    ((f8*)sb.ab)[t] = qb;

    // ---- psqt from compact L2-resident table (ft_bias cancels in wps-bps) ----
    const int pi = psqt_idx[b];
    if (t < 64) {
        const int k = t & 31;
        const int   idx = (t < 32) ? widx[kb + k] : bidx[kb + k];
        const float val = (t < 32) ? wval[kb + k] : bval[kb + k];
        float c = val * psqtc[(size_t)idx * 8 + pi];
        c += __shfl_down(c, 16, 32); c += __shfl_down(c, 8, 32);
        c += __shfl_down(c, 4, 32);  c += __shfl_down(c, 2, 32);
        c += __shfl_down(c, 1, 32);
        const float bsum = __shfl(c, 32);
        if (t == 0) sb.psq = (c - bsum) * (usv - 0.5f);
    }
    __syncthreads();

    // ---- pairwise product ----
    if (t < 128) {
        const f8 x = ((const f8*)sb.aw)[t];
        const f8 y = ((const f8*)sb.aw)[t + 128];
        ((f8*)sb.aw)[t] = x * y;
    } else {
        const f8 x = ((const f8*)sb.ab)[t - 128];
        const f8 y = ((const f8*)sb.ab)[t];
        ((f8*)sb.ab)[t - 128] = x * y;
    }
    __syncthreads();

    // ---- h1 = clip(W1[i] @ m + b1[i]); 16 threads/output ----
    const int i = ls_idx[b];
    {
        const int o   = t >> 4;
        const int sub = t & 15;
        const us8* Wrow = (const us8*)(w1bf + (((size_t)i * 16 + o) << 11));
        f8 a8 = (f8)0.f;
        #pragma unroll
        for (int jj = 0; jj < 8; ++jj) {
            const int c = sub + (jj << 4);
            const f8 m = ((const f8*)sb.aw)[c];
            const us8 w = Wrow[c];
            #pragma unroll
            for (int j = 0; j < 8; ++j) a8[j] = fmaf(m[j], bf2f(w[j]), a8[j]);
        }
        #pragma unroll
        for (int jj = 8; jj < 16; ++jj) {
            const int c = sub + ((jj - 8) << 4);
            const f8 m = ((const f8*)sb.ab)[c];
            const us8 w = Wrow[sub + (jj << 4)];
            #pragma unroll
            for (int j = 0; j < 8; ++j) a8[j] = fmaf(m[j], bf2f(w[j]), a8[j]);
        }
        float acc1 = ((a8[0]+a8[1]) + (a8[2]+a8[3])) + ((a8[4]+a8[5]) + (a8[6]+a8[7]));
        acc1 += __shfl_down(acc1, 8, 16); acc1 += __shfl_down(acc1, 4, 16);
        acc1 += __shfl_down(acc1, 2, 16); acc1 += __shfl_down(acc1, 1, 16);
        if (sub == 0) sb.h1t[o] = acc1;
    }
    __syncthreads();

    if (t < 16) {
        const float v = sb.h1t[t] + b1[i * 16 + t];
        sb.h1[t] = fminf(fmaxf(v, 0.f), 1.f);
    }
    __syncthreads();

    if (t < 32) {
        const float* W2i = W2 + (size_t)i * 32 * 16 + t * 16;
        float v = b2[i * 32 + t];
        #pragma unroll
        for (int j = 0; j < 16; ++j) v = fmaf(sb.h1[j], W2i[j], v);
        sb.h2[t] = fminf(fmaxf(v, 0.f), 1.f);
    }
    __syncthreads();

    if (t == 0) {
        const float* Woi = Wo + (size_t)i * 32;
        float v = bo[i];
        #pragma unroll
        for (int j = 0; j < 32; ++j) v = fmaf(sb.h2[j], Woi[j], v);
        out[b] = v + sb.psq;
    }
}

// ---- fallback: fully fused fp32 (only if ws too small) ----
__global__ __launch_bounds__(512, 4) void nnue_fwd_f32(
    const float* __restrict__ us_p, const float* __restrict__ them_p,
    const int* __restrict__ widx, const float* __restrict__ wval,
    const int* __restrict__ bidx, const float* __restrict__ bval,
    const int* __restrict__ psqt_idx, const int* __restrict__ ls_idx,
    const float* __restrict__ ftw, const float* __restrict__ ftb,
    const float* __restrict__ lsq_s, const float* __restrict__ W1,
    const float* __restrict__ b1, const float* __restrict__ W2,
    const float* __restrict__ b2, const float* __restrict__ Wo,
    const float* __restrict__ bo, float* __restrict__ out)
{
    const int b = blockIdx.x;
    const int t = threadIdx.x;
    __shared__ float4 sQA[512]; __shared__ float4 sQB[512]; __shared__ float4 sMx[512];
    __shared__ float sH1t[16]; __shared__ float sH1[16]; __shared__ float sH2[32];
    __shared__ float sPsq;
    const float usv = us_p[b]; const float thv = them_p[b];
    float4 aw = {0,0,0,0}, ab = {0,0,0,0};
    #pragma unroll 4
    for (int k = 0; k < K; ++k) {
        const int iw = widx[b*K+k]; const float vw = wval[b*K+k];
        const int ibx = bidx[b*K+k]; const float vb = bval[b*K+k];
        fma4(aw, vw, ((const float4*)(ftw + (size_t)iw * ROW))[t]);
        fma4(ab, vb, ((const float4*)(ftw + (size_t)ibx * ROW))[t]);
    }
    const int pi = psqt_idx[b];
    if (t < 64) {
        const int k = t & 31;
        const int   idx = (t < 32) ? widx[b*K+k] : bidx[b*K+k];
        const float val = (t < 32) ? wval[b*K+k] : bval[b*K+k];
        float cc = val * ftw[(size_t)idx * ROW + 2048 + pi];
        cc += __shfl_down(cc, 16, 32); cc += __shfl_down(cc, 8, 32);
        cc += __shfl_down(cc, 4, 32); cc += __shfl_down(cc, 2, 32); cc += __shfl_down(cc, 1, 32);
        const float bsum = __shfl(cc, 32);
        if (t == 0) sPsq = (cc - bsum) * (usv - 0.5f);
    }
    const float s0 = lsq_s[0], s1 = lsq_s[1], s2 = lsq_s[2], s3 = lsq_s[3];
    const float4 bias = ((const float4*)ftb)[t];
    aw = add4(aw, bias); ab = add4(ab, bias);
    const float sA = (t < 256) ? s0 : s1;
    const float sB = (t < 256) ? s2 : s3;
    sQA[t] = lsq4(mix4(usv, aw, thv, ab), sA);
    sQB[t] = lsq4(mix4(usv, ab, thv, aw), sB);
    __syncthreads();
    if (t < 256) { sMx[t] = mul4(sQA[t], sQA[t+256]); sMx[t+256] = mul4(sQB[t], sQB[t+256]); }
    __syncthreads();
    const int i = ls_idx[b];
    const float* W1i = W1 + (size_t)i * 16 * L1D;
    {
        const int o = t >> 5; const int sub = t & 31;
        const float4* Wrow = (const float4*)(W1i + o * L1D);
        float4 a4 = {0,0,0,0};
        #pragma unroll
        for (int jj = 0; jj < 16; ++jj) {
            const int j4 = sub + (jj << 5);
            const float4 m = sMx[j4]; const float4 w = Wrow[j4];
            a4.x = fmaf(m.x, w.x, a4.x); a4.y = fmaf(m.y, w.y, a4.y);
            a4.z = fmaf(m.z, w.z, a4.z); a4.w = fmaf(m.w, w.w, a4.w);
        }
        float acc = (a4.x + a4.y) + (a4.z + a4.w);
        acc += __shfl_down(acc, 16, 32); acc += __shfl_down(acc, 8, 32);
        acc += __shfl_down(acc, 4, 32); acc += __shfl_down(acc, 2, 32); acc += __shfl_down(acc, 1, 32);
        if (sub == 0) sH1t[o] = acc;
    }
    __syncthreads();
    if (t < 16) sH1[t] = fminf(fmaxf(sH1t[t] + b1[i*16+t], 0.f), 1.f);
    __syncthreads();
    if (t < 32) {
        const float* W2i = W2 + (size_t)i * 32 * 16 + t * 16;
        float v = b2[i*32+t];
        #pragma unroll
        for (int j = 0; j < 16; ++j) v = fmaf(sH1[j], W2i[j], v);
        sH2[t] = fminf(fmaxf(v, 0.f), 1.f);
    }
    __syncthreads();
    if (t == 0) {
        const float* Woi = Wo + (size_t)i * 32;
        float v = bo[i];
        #pragma unroll
        for (int j = 0; j < 32; ++j) v = fmaf(sH2[j], Woi[j], v);
        out[b] = v + sPsq;
    }
}

extern "C" void kernel_launch(void* const* d_in, const int* in_sizes, int n_in,
                              void* d_out, int out_size, void* d_ws, size_t ws_size,
                              hipStream_t stream) {
    const float* us_p  = (const float*)d_in[0];
    const float* them  = (const float*)d_in[1];
    const int*   widx  = (const int*)d_in[2];
    const float* wval  = (const float*)d_in[3];
    const int*   bidx  = (const int*)d_in[4];
    const float* bval  = (const float*)d_in[5];
    const int*   pidx  = (const int*)d_in[6];
    const int*   lidx  = (const int*)d_in[7];
    const float* ftw   = (const float*)d_in[8];
    const float* ftb   = (const float*)d_in[9];
    const float* lsqs  = (const float*)d_in[10];
    const float* W1    = (const float*)d_in[11];
    const float* b1    = (const float*)d_in[12];
    const float* W2    = (const float*)d_in[13];
    const float* b2    = (const float*)d_in[14];
    const float* Wo    = (const float*)d_in[15];
    const float* bo    = (const float*)d_in[16];
    float* out = (float*)d_out;

    if (ws_size >= WS_NEEDED) {
        signed char*    tblT  = (signed char*)d_ws;
        unsigned short* w1bf  = (unsigned short*)((char*)d_ws + W1_OFF);
        float*          psqtc = (float*)((char*)d_ws + PSQ_OFF);
        float*          accW  = (float*)((char*)d_ws + ACCW_OFF);
        float*          accB  = (float*)((char*)d_ws + ACCB_OFF);
        conv_all<<<dim3(8192), dim3(256), 0, stream>>>(ftw, W1, tblT, w1bf, psqtc);
        gather_tiled<<<dim3(2048), dim3(256), 0, stream>>>(
            tblT, widx, wval, bidx, bval, accW, accB);
        phase2<<<dim3(BB), dim3(256), 0, stream>>>(
            us_p, them, widx, wval, bidx, bval, pidx, lidx,
            ftb, lsqs, accW, accB, w1bf, psqtc, b1, W2, b2, Wo, bo, out);
    } else {
        nnue_fwd_f32<<<dim3(BB), dim3(512), 0, stream>>>(
            us_p, them, widx, wval, bidx, bval, pidx, lidx,
            ftw, ftb, lsqs, W1, b1, W2, b2, Wo, bo, out);
    }
}